// Round 8
// baseline (488.478 us; speedup 1.0000x reference)
//
#include <hip/hip_runtime.h>

typedef short s16x8 __attribute__((ext_vector_type(8)));
typedef float f32x4 __attribute__((ext_vector_type(4)));

#define LDW 136    // padded LDS row stride in shorts (128 + 8)
#define CAP 10240  // padded bin segment capacity (mean 8192, sigma~90 -> 22 sigma headroom)
#define MAXB 384   // max 3*NB bins supported (N <= 131072; src fits 20 bits in pair)

__device__ __forceinline__ unsigned short f2bf(float x) {
    unsigned int u = __builtin_bit_cast(unsigned int, x);
    u = (u + 0x7fffu + ((u >> 16) & 1u)) >> 16;   // RNE
    return (unsigned short)u;
}
__device__ __forceinline__ float bf2f(unsigned int lo) {
    return __builtin_bit_cast(float, lo << 16);
}

// ---- PREP: blocks [0,pa) = dual src+dst binning; [pa,pa+384) = W->bf16T;
//      [pa+384,..) = x fp32 -> bf16 ----
__global__ __launch_bounds__(256) void prep_kernel(const float* __restrict__ x,
                                                   const float* __restrict__ W1,
                                                   const float* __restrict__ W2,
                                                   const int* __restrict__ src,
                                                   const int* __restrict__ dst,
                                                   int* __restrict__ bincntO,
                                                   int* __restrict__ bincntD,
                                                   unsigned short* __restrict__ srcbin,
                                                   unsigned int* __restrict__ pair,
                                                   unsigned short* __restrict__ WbfT,
                                                   unsigned short* __restrict__ xbf,
                                                   int RE, int E, int N, int NB, int pa) {
    __shared__ int histS[MAXB];
    __shared__ int histD[MAXB];
    int tid = threadIdx.x;
    int bid = blockIdx.x;

    if (bid >= pa + 384) {
        // ---- xconv branch: 8 shorts/thread ----
        int total = N * 128;
        int i8 = (bid - pa - 384) * 2048 + tid * 8;
        if (i8 + 8 <= total) {
            float4 a = ((const float4*)x)[i8 / 4];
            float4 b = ((const float4*)x)[i8 / 4 + 1];
            ushort4 lo = make_ushort4(f2bf(a.x), f2bf(a.y), f2bf(a.z), f2bf(a.w));
            ushort4 hi = make_ushort4(f2bf(b.x), f2bf(b.y), f2bf(b.z), f2bf(b.w));
            *(ushort4*)(xbf + i8) = lo;
            *(ushort4*)(xbf + i8 + 4) = hi;
        } else {
            for (int k = 0; k < 8; ++k)
                if (i8 + k < total) xbf[i8 + k] = f2bf(x[i8 + k]);
        }
        return;
    }
    if (bid >= pa) {
        // ---- wconv branch: WbfT[which][n][k] = bf16(W[which][k][n]) ----
        int idx = (bid - pa) * 256 + tid;
        int which = idx >> 14;
        int k = (idx >> 7) & 127;
        int n = idx & 127;
        int outi = (idx & ~16383) | (n << 7) | k;
        const float* W = (which < 3) ? (W1 + (size_t)which * 16384)
                                     : (W2 + (size_t)(which - 3) * 16384);
        WbfT[outi] = f2bf(W[k * 128 + n]);
        return;
    }

    // ---- dual-binning branch ----
    int ebase = bid * 4096;
    int NB3 = 3 * NB;
    int vs[16], vd[16];
    for (int t = tid; t < MAXB; t += 256) { histS[t] = 0; histD[t] = 0; }
    __syncthreads();
#pragma unroll
    for (int j = 0; j < 16; ++j) {
        int i = ebase + j * 256 + tid;
        vs[j] = 0; vd[j] = 0;
        if (i < RE) {
            vs[j] = src[i]; vd[j] = dst[i];
            int r = (i >= 2 * E) ? 2 : ((i >= E) ? 1 : 0);
            atomicAdd(&histS[r * NB + (vs[j] >> 10)], 1);
            atomicAdd(&histD[r * NB + (vd[j] >> 10)], 1);
        }
    }
    __syncthreads();
    for (int t = tid; t < NB3; t += 256) {
        int cS = histS[t]; histS[t] = cS ? atomicAdd(&bincntO[t], cS) : 0;
        int cD = histD[t]; histD[t] = cD ? atomicAdd(&bincntD[t], cD) : 0;
    }
    __syncthreads();
#pragma unroll
    for (int j = 0; j < 16; ++j) {
        int i = ebase + j * 256 + tid;
        if (i < RE) {
            int r = (i >= 2 * E) ? 2 : ((i >= E) ? 1 : 0);
            int gS = r * NB + (vs[j] >> 10);
            int pS = atomicAdd(&histS[gS], 1);
            if (pS < CAP) srcbin[(size_t)gS * CAP + pS] = (unsigned short)(vs[j] & 1023);
            int gD = r * NB + (vd[j] >> 10);
            int pD = atomicAdd(&histD[gD], 1);
            if (pD < CAP)
                pair[(size_t)gD * CAP + pD] =
                    ((unsigned)(vd[j] & 1023) << 20) | (unsigned)vs[j];
        }
    }
}

// ---- FUSED: blocks [0,NB3) = out-degree histogram -> normO;
//      blocks [NB3,2*NB3) = per-(r,bin) LDS counting sort -> cntI/normI/offs/bucket ----
__global__ __launch_bounds__(256) void histsort_kernel(const unsigned short* __restrict__ srcbin,
                                                       const int* __restrict__ bincntO,
                                                       const unsigned int* __restrict__ pair,
                                                       const int* __restrict__ bincntD,
                                                       float* __restrict__ normO,
                                                       unsigned int* __restrict__ cntI,
                                                       float* __restrict__ normI,
                                                       int* __restrict__ offs,
                                                       int* __restrict__ bucket,
                                                       int N, int NB, int NB3) {
    __shared__ int lcnt[1024], lofs[1024], lcur[1024];
    __shared__ int ws[4];
    int tid = threadIdx.x;

    if ((int)blockIdx.x < NB3) {
        int b = blockIdx.x;
        for (int i = tid; i < 1024; i += 256) lcnt[i] = 0;
        __syncthreads();
        int len = bincntO[b]; if (len > CAP) len = CAP;
        const unsigned short* seg = srcbin + (size_t)b * CAP;
        for (int e = tid; e < len; e += 256)
            atomicAdd(&lcnt[seg[e]], 1);
        __syncthreads();
        int r = b / NB, bin = b - r * NB;
        int node0 = bin << 10;
        for (int i = tid; i < 1024; i += 256) {
            int node = node0 + i;
            if (node < N)
                normO[(size_t)r * N + node] = rsqrtf(fmaxf((float)lcnt[i], 1.0f));
        }
        return;
    }

    int b = blockIdx.x - NB3;
    for (int i = tid; i < 1024; i += 256) { lcnt[i] = 0; lcur[i] = 0; }
    __syncthreads();
    int len = bincntD[b]; if (len > CAP) len = CAP;
    const unsigned int* seg = pair + (size_t)b * CAP;
    for (int e = tid; e < len; e += 256)
        atomicAdd(&lcnt[seg[e] >> 20], 1);
    __syncthreads();
    int i0 = tid * 4;
    int a0 = lcnt[i0], a1 = lcnt[i0 + 1], a2 = lcnt[i0 + 2], a3 = lcnt[i0 + 3];
    int tot = a0 + a1 + a2 + a3;
    int lane = tid & 63, w = tid >> 6;
    int x = tot;
#pragma unroll
    for (int d = 1; d < 64; d <<= 1) { int y = __shfl_up(x, d, 64); if (lane >= d) x += y; }
    if (lane == 63) ws[w] = x;
    __syncthreads();
    int wbase = 0;
    for (int k = 0; k < 4; ++k) if (k < w) wbase += ws[k];
    int pre = wbase + x - tot;
    lofs[i0] = pre;
    lofs[i0 + 1] = pre + a0;
    lofs[i0 + 2] = pre + a0 + a1;
    lofs[i0 + 3] = pre + a0 + a1 + a2;
    __syncthreads();
    int r = b / NB, bin = b - r * NB;
    int node0 = bin << 10;
    int base = b * CAP;
    for (int i = tid; i < 1024; i += 256) {
        int node = node0 + i;
        if (node < N) {
            int c = lcnt[i];
            cntI[(size_t)r * N + node]  = (unsigned int)c;
            normI[(size_t)r * N + node] = rsqrtf(fmaxf((float)c, 1.0f));
            offs[(size_t)r * N + node]  = base + lofs[i];
        }
    }
    for (int e = tid; e < len; e += 256) {
        unsigned int p = seg[e];
        int dl = p >> 20;
        int lr = atomicAdd(&lcur[dl], 1);
        bucket[(size_t)base + lofs[dl] + lr] = (int)(p & 0xFFFFFu);
    }
}

// ---- aggregate-first gather: g[n][r*128+c] = normI_r[n] * sum_e normO_r[src] * X[src][c]
// X is ONE shared [N][128] bf16 array (25.6MB -> L2/L3-resident), R4-proven inner loop. ----
__global__ __launch_bounds__(256) void gather_g(const unsigned short* __restrict__ X,  // [N][128]
                                                const int* __restrict__ bucket,
                                                const int* __restrict__ offs,          // [R][N] ABSOLUTE
                                                const unsigned int* __restrict__ cnt,  // [R][N]
                                                const float* __restrict__ normI,       // [R][N]
                                                const float* __restrict__ normO,       // [R][N]
                                                unsigned short* __restrict__ g,        // [N][384]
                                                int N) {
    int n = blockIdx.x * 4 + (threadIdx.x >> 6);
    if (n >= N) return;
    int lane = threadIdx.x & 63;
    const unsigned int* Xr = (const unsigned int*)X;   // [N][64] uint (2 cols each)
    unsigned int* gw = (unsigned int*)g;               // [N][192]
#pragma unroll
    for (int r = 0; r < 3; ++r) {
        float p0 = 0.f, p1 = 0.f;
        int start = offs[(size_t)r * N + n];
        int c = (int)cnt[(size_t)r * N + n];
        const float* nO = normO + (size_t)r * N;
        const int* bk = bucket + start;
        for (int base = 0; base < c; base += 64) {
            int m = min(64, c - base);
            int id = (lane < m) ? bk[base + lane] : 0;
            float nv = (lane < m) ? nO[id] : 0.f;
            for (int jj = 0; jj < m; jj += 8) {
                int mm = m - jj;                      // wave-uniform
                unsigned int v[8];
#pragma unroll
                for (int u = 0; u < 8; ++u) {
                    int s2 = __shfl(id, jj + u, 64);
                    v[u] = (u < mm) ? Xr[(size_t)s2 * 64 + lane] : 0u;
                }
#pragma unroll
                for (int u = 0; u < 8; ++u) {
                    float sc = __shfl(nv, jj + u, 64);
                    p0 = fmaf(sc, bf2f(v[u] & 0xffffu), p0);
                    p1 = fmaf(sc, bf2f(v[u] >> 16), p1);
                }
            }
        }
        float nd = normI[(size_t)r * N + n];
        unsigned int pk = (unsigned int)f2bf(p0 * nd)
                        | ((unsigned int)f2bf(p1 * nd) << 16);
        gw[(size_t)n * 192 + r * 64 + lane] = pk;
    }
}

// ---- K=384 gemm: out[n] = sum_r g[n][r] @ W_r + sum_r bias_r (+relu) ----
template <bool RELU, bool F32OUT>
__global__ __launch_bounds__(256) void gemm_k384(const unsigned short* __restrict__ G,    // [nrows][384]
                                                 const unsigned short* __restrict__ WbfT, // [3][128n][128k]
                                                 const float* __restrict__ bias,          // [3][128]
                                                 void* __restrict__ out,
                                                 int nrows) {
    __shared__ unsigned short Xl[64 * LDW];
    __shared__ unsigned short Wl[128 * LDW];
    int tid = threadIdx.x;
    int row0 = blockIdx.x * 64;

    int wave = tid >> 6, lane = tid & 63;
    int laneM = lane & 15, quad = lane >> 4;
    int m0 = wave * 16;

    f32x4 acc[8];
#pragma unroll
    for (int ct = 0; ct < 8; ++ct) acc[ct] = (f32x4){0.f, 0.f, 0.f, 0.f};

    for (int r = 0; r < 3; ++r) {
        if (r) __syncthreads();   // protect previous tile reads
#pragma unroll
        for (int j = 0; j < 8; ++j) {
            int f4 = tid + j * 256;
            int row = f4 >> 5;
            int col = f4 & 31;                 // uint2 units (4 shorts)
            int gr = row0 + row;
            uint2 v = make_uint2(0u, 0u);
            if (gr < nrows) v = ((const uint2*)G)[(size_t)gr * 96 + r * 32 + col];
            *(uint2*)(&Xl[row * LDW + col * 4]) = v;
        }
#pragma unroll
        for (int j = 0; j < 8; ++j) {
            int i = tid + j * 256;
            int row = i >> 4, c0 = (i & 15) * 8;
            *(uint4*)(Wl + row * LDW + c0) =
                ((const uint4*)(WbfT + (size_t)r * 16384))[i];
        }
        __syncthreads();

        s16x8 afr[4];
#pragma unroll
        for (int ks = 0; ks < 4; ++ks)
            afr[ks] = *(const s16x8*)(Xl + (m0 + laneM) * LDW + ks * 32 + quad * 8);
#pragma unroll
        for (int ks = 0; ks < 4; ++ks) {
            int k = ks * 32 + quad * 8;
#pragma unroll
            for (int ct = 0; ct < 8; ++ct) {
                s16x8 b = *(const s16x8*)(Wl + (ct * 16 + laneM) * LDW + k);
                acc[ct] = __builtin_amdgcn_mfma_f32_16x16x32_bf16(afr[ks], b, acc[ct], 0, 0, 0);
            }
        }
    }

#pragma unroll
    for (int i = 0; i < 4; ++i) {
        int gr = row0 + m0 + quad * 4 + i;
        if (gr < nrows) {
#pragma unroll
            for (int ct = 0; ct < 8; ++ct) {
                int col = ct * 16 + laneM;
                float val = acc[ct][i] + bias[col] + bias[128 + col] + bias[256 + col];
                if (RELU) val = fmaxf(val, 0.f);
                if (F32OUT) ((float*)out)[(size_t)gr * 128 + col] = val;
                else ((unsigned short*)out)[(size_t)gr * 128 + col] = f2bf(val);
            }
        }
    }
}

extern "C" void kernel_launch(void* const* d_in, const int* in_sizes, int n_in,
                              void* d_out, int out_size, void* d_ws, size_t ws_size,
                              hipStream_t stream) {
    const float* x  = (const float*)d_in[0];
    const int* src  = (const int*)d_in[1];
    const int* dst  = (const int*)d_in[2];
    const float* W1 = (const float*)d_in[3];
    const float* b1 = (const float*)d_in[4];
    const float* W2 = (const float*)d_in[5];
    const float* b2 = (const float*)d_in[6];
    float* out = (float*)d_out;

    const int R = 3;
    int N = in_sizes[0] / 128;
    int E = in_sizes[1] / R;
    int RE = R * E;
    int RN = R * N;
    int NB = (N + 1023) >> 10;
    int NB3 = 3 * NB;
    if (NB3 > MAXB) return;

    size_t outBytes = (size_t)out_size * 4;    // harness reads out as fp32[out_size] (elements!)
    size_t h1b = (size_t)N * 128 * 2;          // bf16 hidden; aliases packed-pair buffer
    size_t gbuf = (size_t)N * 384 * 2;         // gathered g [N][384] bf16
    size_t ib  = (size_t)RN * 4;               // one int/float [R][N] array
    size_t bb  = (size_t)NB3 * CAP * 4;        // padded bucket
    size_t wb  = (size_t)2 * R * 16384 * 2;    // bf16 transposed weights
    size_t bcb = (size_t)((2 * NB3 * 4 + 255) & ~255);  // bincntO + bincntD
    if ((size_t)NB3 * CAP * 4 > h1b) return;             // pair (u32) fits in h1 alias
    if ((size_t)NB3 * CAP * 2 > (size_t)(8 << 20)) return;  // srcbin fits in out[0,8MB) bytes
    if ((size_t)(8 << 20) + h1b > outBytes) return;          // xbf fits in out[8MB,..) bytes
    if (ws_size < h1b + gbuf + 4 * ib + bb + wb + bcb) return;

    char* w = (char*)d_ws;
    unsigned short* h1   = (unsigned short*)w;            w += h1b;
    unsigned short* g    = (unsigned short*)w;            w += gbuf;
    unsigned int* cntI   = (unsigned int*)w;              w += ib;
    float* normO         = (float*)w;                     w += ib;
    float* normI         = (float*)w;                     w += ib;
    int* offs            = (int*)w;                       w += ib;
    int* bucket          = (int*)w;                       w += bb;
    unsigned short* WbfT = (unsigned short*)w;            w += wb;
    int* bincnt          = (int*)w;                       // [2][NB3]

    int* bincntO = bincnt;
    int* bincntD = bincnt + NB3;
    unsigned int* pair     = (unsigned int*)h1;                      // dead before gemm1 writes h1
    unsigned short* srcbin = (unsigned short*)d_out;                 // dead before gemm2 writes out
    unsigned short* xbf    = (unsigned short*)((char*)d_out + (8 << 20)); // dead before gemm2 writes out

    hipMemsetAsync(bincnt, 0, (size_t)2 * NB3 * 4, stream);

    int pa = (RE + 4095) / 4096;
    int xc = (N * 128 + 2047) / 2048;
    int gb = (N + 63) / 64;
    int ngb = (N + 3) / 4;

    // prep: dual binning + W conv + x conv (independent block ranges)
    prep_kernel<<<pa + 384 + xc, 256, 0, stream>>>(x, W1, W2, src, dst,
                                                   bincntO, bincntD, srcbin, pair,
                                                   WbfT, xbf, RE, E, N, NB, pa);

    // fused: out-degree histogram (normO) + counting sort (cntI/normI/offs/bucket)
    histsort_kernel<<<2 * NB3, 256, 0, stream>>>(srcbin, bincntO, pair, bincntD,
                                                 normO, cntI, normI, offs, bucket, N, NB, NB3);

    // layer 1: gather x -> g, then K=384 gemm (+bias sum, relu) -> h1 bf16
    gather_g<<<ngb, 256, 0, stream>>>(xbf, bucket, offs, cntI, normI, normO, g, N);
    gemm_k384<true, false><<<gb, 256, 0, stream>>>(g, WbfT, b1, h1, N);

    // layer 2: gather h1 -> g, then K=384 gemm (+bias sum) -> out fp32
    gather_g<<<ngb, 256, 0, stream>>>(h1, bucket, offs, cntI, normI, normO, g, N);
    gemm_k384<false, true><<<gb, 256, 0, stream>>>(g, WbfT + (size_t)3 * 16384, b2, out, N);
}